// Round 1
// 749.022 us; speedup vs baseline: 1.1005x; 1.1005x over previous
//
#include <hip/hip_runtime.h>

// GraphCNN fused per-graph MFMA kernel (fp16 inputs, fp32 accumulate).
// One workgroup (256 thr = 4 waves) per graph; 2 blocks/CU (LDS 72,192 B).
// Key changes vs prev: bufT eliminated (in-register C->B fragment transpose
// via __shfl_xor lane^32), r1R eliminated (r1 kept in VGPRs for S4; S6 uses
// r1@Wr2 == h0@(Wr1@Wr2) with Wc precomputed in prep), barriers 7->6,
// vectorized adj staging with fused zero-pad.
//
// MFMA layouts (gfx950, verified learn_hip m74/m101/m120):
//   A: A[m][k], m = lane&31, k = (lane>>5)*8 + j   (8 contiguous k -> b128)
//   B: B[k][n], n = lane&31, k = (lane>>5)*8 + j
//   C/D: col = lane&31, row = (reg&3) + 8*(reg>>2) + 4*(lane>>5)

#define NN 90
#define HH 128
#define NT 256

typedef _Float16 half8 __attribute__((ext_vector_type(8)));
typedef _Float16 half2v __attribute__((ext_vector_type(2)));
typedef float floatx16 __attribute__((ext_vector_type(16)));
typedef unsigned int uint4v __attribute__((ext_vector_type(4)));

// adj buffer: [96][AST=104] f16 (row stride 208 B = 52 dw == 20 mod 32: optimal)
#define AST 104
#define AST8 13
#define ASTU 52
// node-major hidden buffers: [96][SR=136] f16 (272 B = 68 dw == 4 mod 32: optimal)
#define SR 136
#define SR8 17

#define MFMA(a, b, c) __builtin_amdgcn_mfma_f32_32x32x16_f16((a), (b), (c), 0, 0, 0)

// ---------------- weight prep ----------------
// ws layout (f16): W0T [128][96] @0 (slot k=90 holds bsum[n]) ; Wr1T @12288 ;
// W1T @28672 ; W2T @45056 ; WcT=(Wr1@Wr2)^T @61440.  Total 77824 f16 (unchanged).
__global__ void prep_weights(const float* __restrict__ W0,
                             const float* __restrict__ Wr1,
                             const float* __restrict__ W1,
                             const float* __restrict__ W2,
                             const float* __restrict__ Wr2,
                             const float* __restrict__ b2,
                             const float* __restrict__ br1,
                             const float* __restrict__ br2,
                             _Float16* __restrict__ ws)
{
    const int idx = blockIdx.x * blockDim.x + threadIdx.x;
    if (idx < 12288) {                       // W0T[n][k], k padded 90->96
        const int nn = idx / 96, k = idx - nn * 96;
        if (k != 90)                         // k==90 reserved for bsum (tail writes)
            ws[idx] = (k < NN) ? (_Float16)W0[k * HH + nn] : (_Float16)0.f;
    } else if (idx < 61440) {                // Wr1T, W1T, W2T  [128][128] transposed
        const int j = idx - 12288;
        const int m = j >> 14;
        const int r = j & 16383;
        const int nn = r >> 7, k = r & 127;
        const float* src = (m == 0) ? Wr1 : (m == 1) ? W1 : W2;
        ws[idx] = (_Float16)src[k * HH + nn];
    } else if (idx < 77824) {                // WcT[n][k] = (Wr1@Wr2)[k][n]
        const int j = idx - 61440;
        const int nn = j >> 7, k = j & 127;
        float s = 0.f;
        for (int q = 0; q < HH; q++) s += Wr1[k * HH + q] * Wr2[q * HH + nn];
        ws[idx] = (_Float16)s;
    } else if (idx < 77952) {                // bsum[n] = b2 + br2 + br1@Wr2
        const int nn = idx - 77824;
        float s = b2[nn] + br2[nn];
        for (int q = 0; q < HH; q++) s += br1[q] * Wr2[q * HH + nn];
        ws[nn * 96 + 90] = (_Float16)s;      // stashed in W0T's zero-pad column
    }
}

// ---------------- main fused kernel ----------------
__global__ __launch_bounds__(NT, 2) void graphcnn_mfma(
    const float* __restrict__ adj,
    const _Float16* __restrict__ wts,
    const float* __restrict__ b0, const float* __restrict__ b1,
    const float* __restrict__ br1,
    float* __restrict__ out)
{
    // LDS: adjH [96][104] | B1 [96][136] (tR->uR) | B2 [96][136] (h0R->YR)
    __shared__ __align__(16) unsigned char smem[72192];
    _Float16* adjH = (_Float16*)smem;
    _Float16* B1   = (_Float16*)(smem + 19968);
    _Float16* B2   = (_Float16*)(smem + 46080);

    const int t    = threadIdx.x;
    const int wv   = t >> 6;
    const int lane = t & 63;
    const int p    = lane & 31;
    const int h    = lane >> 5;
    const int n    = wv * 32 + p;      // hidden column owned by this thread

    const _Float16* W0T  = wts;                 // [128][96]
    const _Float16* Wr1T = wts + 12288;         // [128][128]
    const _Float16* W1T  = wts + 28672;
    const _Float16* W2T  = wts + 45056;
    const _Float16* WcT  = wts + 61440;

    // ---- stage adj fp32->fp16 with fused zero-pad (rows/cols 90..95 -> 0) ----
    {
        const float* Ag = adj + (size_t)blockIdx.x * (NN * NN);
        unsigned* aH = (unsigned*)adjH;
        #pragma unroll
        for (int it = 0; it < 18; it++) {
            const int i = t + it * NT;          // 0..4607 = 96 rows * 48 u32
            const int r = i / 48, cc = i - r * 48;
            unsigned val = 0u;
            if (r < NN && cc < 45) {
                const float2 v = *(const float2*)(Ag + r * NN + cc * 2);
                const half2v hv = { (_Float16)v.x, (_Float16)v.y };
                val = __builtin_bit_cast(unsigned, hv);
            }
            aH[r * ASTU + cc] = val;
        }
    }

    // C-registers -> row-major LDS
    auto writeR = [&](_Float16* buf, const floatx16& A0, const floatx16& A1,
                      const floatx16& A2) {
        #pragma unroll
        for (int mt = 0; mt < 3; mt++) {
            const floatx16& A = (mt == 0) ? A0 : (mt == 1) ? A1 : A2;
            #pragma unroll
            for (int r = 0; r < 16; r++) {
                const int node = mt * 32 + (r & 3) + 8 * (r >> 2) + 4 * h;
                buf[node * SR + n] = (_Float16)A[r];
            }
        }
    };

    // C-registers -> B-fragments (for next adj@X matmul), pure in-register:
    // consumer lane (p,h) needs B[k=16kt+8h+j][n]; source is lane (p, h_owner)
    // reg (j&3)+8(kt&1)+4h.  Exchange across lane^32 via __shfl_xor.
    uint4v frg[6];
    auto buildFrags = [&](const floatx16& A0, const floatx16& A1, const floatx16& A2) {
        #pragma unroll
        for (int mt = 0; mt < 3; mt++) {
            const floatx16& A = (mt == 0) ? A0 : (mt == 1) ? A1 : A2;
            #pragma unroll
            for (int s01 = 0; s01 < 2; s01++) {
                const int s = 8 * s01;
                const half2v x0 = { (_Float16)A[s + 0], (_Float16)A[s + 1] };
                const half2v x1 = { (_Float16)A[s + 2], (_Float16)A[s + 3] };
                const half2v y0 = { (_Float16)A[s + 4], (_Float16)A[s + 5] };
                const half2v y1 = { (_Float16)A[s + 6], (_Float16)A[s + 7] };
                const unsigned X0 = __builtin_bit_cast(unsigned, x0);
                const unsigned X1 = __builtin_bit_cast(unsigned, x1);
                const unsigned Y0 = __builtin_bit_cast(unsigned, y0);
                const unsigned Y1 = __builtin_bit_cast(unsigned, y1);
                const unsigned R0 = __shfl_xor(h ? X0 : Y0, 32, 64);
                const unsigned R1 = __shfl_xor(h ? X1 : Y1, 32, 64);
                uint4v f;
                f[0] = h ? R0 : X0;
                f[1] = h ? R1 : X1;
                f[2] = h ? Y0 : R0;
                f[3] = h ? Y1 : R1;
                frg[mt * 2 + s01] = f;
            }
        }
    };

    __syncthreads();

    floatx16 acc0, acc1, acc2;

    // ===== S1: h0 = adj @ W0 + b0 -> h0R (B2) + B-frags =====
    {
        half8 bw[6];
        #pragma unroll
        for (int kt = 0; kt < 6; kt++) bw[kt] = ((const half8*)W0T)[n * 12 + kt * 2 + h];
        const float bias = b0[n];
        #pragma unroll
        for (int r = 0; r < 16; r++) { acc0[r] = bias; acc1[r] = bias; acc2[r] = bias; }
        #pragma unroll
        for (int kt = 0; kt < 6; kt++) {
            const half8 a0 = ((const half8*)adjH)[(0 * 32 + p) * AST8 + kt * 2 + h];
            const half8 a1 = ((const half8*)adjH)[(1 * 32 + p) * AST8 + kt * 2 + h];
            const half8 a2 = ((const half8*)adjH)[(2 * 32 + p) * AST8 + kt * 2 + h];
            acc0 = MFMA(a0, bw[kt], acc0);
            acc1 = MFMA(a1, bw[kt], acc1);
            acc2 = MFMA(a2, bw[kt], acc2);
        }
        writeR(B2, acc0, acc1, acc2);
        buildFrags(acc0, acc1, acc2);
    }

    // ===== S3: t = adj @ h0 (B from regs) -> tR (B1); no barrier needed =====
    {
        #pragma unroll
        for (int r = 0; r < 16; r++) { acc0[r] = 0.f; acc1[r] = 0.f; acc2[r] = 0.f; }
        #pragma unroll
        for (int kt = 0; kt < 6; kt++) {
            const half8 bfk = __builtin_bit_cast(half8, frg[kt]);
            const half8 a0 = ((const half8*)adjH)[(0 * 32 + p) * AST8 + kt * 2 + h];
            const half8 a1 = ((const half8*)adjH)[(1 * 32 + p) * AST8 + kt * 2 + h];
            const half8 a2 = ((const half8*)adjH)[(2 * 32 + p) * AST8 + kt * 2 + h];
            acc0 = MFMA(a0, bfk, acc0);
            acc1 = MFMA(a1, bfk, acc1);
            acc2 = MFMA(a2, bfk, acc2);
        }
        writeR(B1, acc0, acc1, acc2);
    }
    __syncthreads();    // h0R visible for S2; tR visible for S4

    // ===== S2: r1 = h0R @ Wr1 + br1 (kept in registers for S4) =====
    floatx16 r1a, r1b, r1c;
    {
        half8 bw[8];
        #pragma unroll
        for (int kt = 0; kt < 8; kt++) bw[kt] = ((const half8*)Wr1T)[n * 16 + kt * 2 + h];
        const float bias = br1[n];
        #pragma unroll
        for (int r = 0; r < 16; r++) { r1a[r] = bias; r1b[r] = bias; r1c[r] = bias; }
        #pragma unroll
        for (int kt = 0; kt < 8; kt++) {
            const half8 a0 = ((const half8*)B2)[(0 * 32 + p) * SR8 + kt * 2 + h];
            const half8 a1 = ((const half8*)B2)[(1 * 32 + p) * SR8 + kt * 2 + h];
            const half8 a2 = ((const half8*)B2)[(2 * 32 + p) * SR8 + kt * 2 + h];
            r1a = MFMA(a0, bw[kt], r1a);
            r1b = MFMA(a1, bw[kt], r1b);
            r1c = MFMA(a2, bw[kt], r1c);
        }
    }

    // ===== S4: x = relu(tR @ W1 + b1) + r1 -> B-frags only (no LDS write) =====
    {
        half8 bw[8];
        #pragma unroll
        for (int kt = 0; kt < 8; kt++) bw[kt] = ((const half8*)W1T)[n * 16 + kt * 2 + h];
        const float bias = b1[n];
        #pragma unroll
        for (int r = 0; r < 16; r++) { acc0[r] = bias; acc1[r] = bias; acc2[r] = bias; }
        #pragma unroll
        for (int kt = 0; kt < 8; kt++) {
            const half8 a0 = ((const half8*)B1)[(0 * 32 + p) * SR8 + kt * 2 + h];
            const half8 a1 = ((const half8*)B1)[(1 * 32 + p) * SR8 + kt * 2 + h];
            const half8 a2 = ((const half8*)B1)[(2 * 32 + p) * SR8 + kt * 2 + h];
            acc0 = MFMA(a0, bw[kt], acc0);
            acc1 = MFMA(a1, bw[kt], acc1);
            acc2 = MFMA(a2, bw[kt], acc2);
        }
        #pragma unroll
        for (int r = 0; r < 16; r++) {
            acc0[r] = fmaxf(acc0[r], 0.f) + r1a[r];
            acc1[r] = fmaxf(acc1[r], 0.f) + r1b[r];
            acc2[r] = fmaxf(acc2[r], 0.f) + r1c[r];
        }
        buildFrags(acc0, acc1, acc2);
    }
    __syncthreads();    // all tR reads done before uR overwrites B1

    // ===== S5: u = adj @ x (B from regs) -> uR (B1) =====
    {
        #pragma unroll
        for (int r = 0; r < 16; r++) { acc0[r] = 0.f; acc1[r] = 0.f; acc2[r] = 0.f; }
        #pragma unroll
        for (int kt = 0; kt < 6; kt++) {
            const half8 bfk = __builtin_bit_cast(half8, frg[kt]);
            const half8 a0 = ((const half8*)adjH)[(0 * 32 + p) * AST8 + kt * 2 + h];
            const half8 a1 = ((const half8*)adjH)[(1 * 32 + p) * AST8 + kt * 2 + h];
            const half8 a2 = ((const half8*)adjH)[(2 * 32 + p) * AST8 + kt * 2 + h];
            acc0 = MFMA(a0, bfk, acc0);
            acc1 = MFMA(a1, bfk, acc1);
            acc2 = MFMA(a2, bfk, acc2);
        }
        writeR(B1, acc0, acc1, acc2);
    }
    __syncthreads();    // uR visible; adjH reads complete

    // ===== S6: Y = relu(uR@W2 + h0R@Wc + bsum)  (r1@Wr2 folded into h0@Wc) =====
    {
        half8 bw[8], bg[8];
        #pragma unroll
        for (int kt = 0; kt < 8; kt++) {
            bw[kt] = ((const half8*)W2T)[n * 16 + kt * 2 + h];
            bg[kt] = ((const half8*)WcT)[n * 16 + kt * 2 + h];
        }
        const float bias = (float)W0T[n * 96 + 90];   // bsum = b2 + br2 + br1@Wr2
        #pragma unroll
        for (int r = 0; r < 16; r++) { acc0[r] = bias; acc1[r] = bias; acc2[r] = bias; }
        #pragma unroll
        for (int kt = 0; kt < 8; kt++) {
            const half8 a0 = ((const half8*)B1)[(0 * 32 + p) * SR8 + kt * 2 + h];
            const half8 a1 = ((const half8*)B1)[(1 * 32 + p) * SR8 + kt * 2 + h];
            const half8 a2 = ((const half8*)B1)[(2 * 32 + p) * SR8 + kt * 2 + h];
            acc0 = MFMA(a0, bw[kt], acc0);
            acc1 = MFMA(a1, bw[kt], acc1);
            acc2 = MFMA(a2, bw[kt], acc2);
        }
        #pragma unroll
        for (int kt = 0; kt < 8; kt++) {
            const half8 a0 = ((const half8*)B2)[(0 * 32 + p) * SR8 + kt * 2 + h];
            const half8 a1 = ((const half8*)B2)[(1 * 32 + p) * SR8 + kt * 2 + h];
            const half8 a2 = ((const half8*)B2)[(2 * 32 + p) * SR8 + kt * 2 + h];
            acc0 = MFMA(a0, bg[kt], acc0);
            acc1 = MFMA(a1, bg[kt], acc1);
            acc2 = MFMA(a2, bg[kt], acc2);
        }
    }
    __syncthreads();    // all h0R reads done before YR overwrites B2
    {
        _Float16* YR = B2;
        #pragma unroll
        for (int mt = 0; mt < 3; mt++) {
            const floatx16& A = (mt == 0) ? acc0 : (mt == 1) ? acc1 : acc2;
            #pragma unroll
            for (int r = 0; r < 16; r++) {
                const int node = mt * 32 + (r & 3) + 8 * (r >> 2) + 4 * h;
                YR[node * SR + n] = (_Float16)fmaxf(A[r], 0.f);
            }
        }
    }
    __syncthreads();

    // ===== S7: Z = Y @ Y^T -> out (both operands from YR row-major) =====
    {
        const _Float16* YR = B2;
        float* outb = out + (size_t)blockIdx.x * (NN * NN);
        auto ztile = [&](int mt, int nt) {
            floatx16 acc;
            #pragma unroll
            for (int r = 0; r < 16; r++) acc[r] = 0.f;
            #pragma unroll
            for (int kt = 0; kt < 8; kt++) {
                const half8 av = ((const half8*)YR)[(mt * 32 + p) * SR8 + kt * 2 + h];
                const half8 bv = ((const half8*)YR)[(nt * 32 + p) * SR8 + kt * 2 + h];
                acc = MFMA(av, bv, acc);
            }
            const int col = nt * 32 + p;
            if (col < NN) {
                #pragma unroll
                for (int r = 0; r < 16; r++) {
                    const int row = mt * 32 + (r & 3) + 8 * (r >> 2) + 4 * h;
                    if (row < NN) outb[row * NN + col] = acc[r];
                }
            }
        };
        if      (wv == 0) { ztile(0, 0); ztile(0, 1); ztile(0, 2); }
        else if (wv == 1) { ztile(1, 0); ztile(1, 1); }
        else if (wv == 2) { ztile(1, 2); ztile(2, 0); }
        else              { ztile(2, 1); ztile(2, 2); }
    }
}

extern "C" void kernel_launch(void* const* d_in, const int* in_sizes, int n_in,
                              void* d_out, int out_size, void* d_ws, size_t ws_size,
                              hipStream_t stream) {
    const float* adj = (const float*)d_in[0];
    const float* W0  = (const float*)d_in[1];
    const float* b0  = (const float*)d_in[2];
    const float* W1  = (const float*)d_in[3];
    const float* b1  = (const float*)d_in[4];
    const float* W2  = (const float*)d_in[5];
    const float* b2  = (const float*)d_in[6];
    const float* Wr1 = (const float*)d_in[7];
    const float* br1 = (const float*)d_in[8];
    const float* Wr2 = (const float*)d_in[9];
    const float* br2 = (const float*)d_in[10];
    float* out = (float*)d_out;
    _Float16* wts = (_Float16*)d_ws;

    prep_weights<<<77, 1024, 0, stream>>>(W0, Wr1, W1, W2, Wr2, b2, br1, br2, wts);

    const int B = in_sizes[0] / (NN * NN);
    graphcnn_mfma<<<B, NT, 0, stream>>>(adj, wts, b0, b1, br1, out);
}

// Round 2
// 680.958 us; speedup vs baseline: 1.2105x; 1.1000x over previous
//
#include <hip/hip_runtime.h>

// GraphCNN fused per-graph MFMA kernel (fp16 inputs, fp32 accumulate).
// One workgroup (256 thr = 4 waves) per graph; 3 blocks/CU (LDS 46,080 B).
// Key changes vs prev: h0 LDS buffer (B2) eliminated algebraically:
//   r1 = h0@Wr1 + br1           == adj@Wd + c1,      Wd = W0@Wr1
//   r1@Wr2 (inside S6)          == adj@We + (bsum),  We = Wd@Wr2
// so S2/S6 read adjH fragments (K=96, 18 MFMAs) instead of h0R (K=128, 24).
// h0 feeds S3 only via in-register C->B frag transpose. YR overlays B1.
// r1 kept packed fp16 in VGPRs. Barriers: 6.
//
// MFMA layouts (gfx950, verified learn_hip m74/m101/m120):
//   A: A[m][k], m = lane&31, k = (lane>>5)*8 + j   (8 contiguous k -> b128)
//   B: B[k][n], n = lane&31, k = (lane>>5)*8 + j
//   C/D: col = lane&31, row = (reg&3) + 8*(reg>>2) + 4*(lane>>5)

#define NN 90
#define HH 128
#define NT 256

typedef _Float16 half8 __attribute__((ext_vector_type(8)));
typedef _Float16 half2v __attribute__((ext_vector_type(2)));
typedef float floatx16 __attribute__((ext_vector_type(16)));
typedef unsigned int uint4v __attribute__((ext_vector_type(4)));

// adj buffer: [96][AST=104] f16 (row stride 208 B = 52 dw == 20 mod 32: optimal)
#define AST 104
#define AST8 13
#define ASTU 52
// node-major hidden buffer: [96][SR=136] f16 (272 B = 68 dw == 4 mod 32: optimal)
#define SR 136
#define SR8 17

#define MFMA(a, b, c) __builtin_amdgcn_mfma_f32_32x32x16_f16((a), (b), (c), 0, 0, 0)

// ---------------- weight prep ----------------
// ws layout (f16 elems): W0T [128][96] @0 | WdT [128][96] @12288 (col90 = c1)
//   | WeT [128][96] @24576 (col90 = bsum) | W1T [128][128] @36864
//   | W2T [128][128] @53248.  End f16 @69632 (139,264 B).
// fp32 scratch: WdF [90][128] @byte 139264 ; c1F [128] @byte 185344.
__global__ void prep_stage1(const float* __restrict__ W0,
                            const float* __restrict__ Wr1,
                            const float* __restrict__ b0,
                            const float* __restrict__ br1,
                            float* __restrict__ WdF,
                            float* __restrict__ c1F)
{
    const int idx = blockIdx.x * blockDim.x + threadIdx.x;
    if (idx < NN * HH) {                 // Wd[k][n] = sum_q W0[k][q] Wr1[q][n]
        const int k = idx >> 7, nn = idx & 127;
        float s = 0.f;
        for (int q = 0; q < HH; q++) s += W0[k * HH + q] * Wr1[q * HH + nn];
        WdF[idx] = s;
    } else if (idx < NN * HH + HH) {     // c1[n] = b0@Wr1 + br1
        const int nn = idx - NN * HH;
        float s = br1[nn];
        for (int q = 0; q < HH; q++) s += b0[q] * Wr1[q * HH + nn];
        c1F[nn] = s;
    }
}

__global__ void prep_stage2(const float* __restrict__ W0,
                            const float* __restrict__ W1,
                            const float* __restrict__ W2,
                            const float* __restrict__ Wr2,
                            const float* __restrict__ b2,
                            const float* __restrict__ br2,
                            const float* __restrict__ WdF,
                            const float* __restrict__ c1F,
                            _Float16* __restrict__ ws)
{
    const int idx = blockIdx.x * blockDim.x + threadIdx.x;
    if (idx < 12288) {                       // W0T[n][k], k padded 90->96 w/ zeros
        const int nn = idx / 96, k = idx - nn * 96;
        ws[idx] = (k < NN) ? (_Float16)W0[k * HH + nn] : (_Float16)0.f;
    } else if (idx < 24576) {                // WdT[n][k]; col 90 = c1[n]
        const int j = idx - 12288;
        const int nn = j / 96, k = j - nn * 96;
        _Float16 v = (_Float16)0.f;
        if (k < NN)       v = (_Float16)WdF[k * HH + nn];
        else if (k == NN) v = (_Float16)c1F[nn];
        ws[idx] = v;
    } else if (idx < 36864) {                // WeT[n][k] = (Wd@Wr2)[k][n]; col90=bsum
        const int j = idx - 24576;
        const int nn = j / 96, k = j - nn * 96;
        _Float16 v = (_Float16)0.f;
        if (k < NN) {
            float s = 0.f;
            for (int q = 0; q < HH; q++) s += WdF[k * HH + q] * Wr2[q * HH + nn];
            v = (_Float16)s;
        } else if (k == NN) {                // bsum = b2 + br2 + c1@Wr2
            float s = b2[nn] + br2[nn];
            for (int q = 0; q < HH; q++) s += c1F[q] * Wr2[q * HH + nn];
            v = (_Float16)s;
        }
        ws[idx] = v;
    } else if (idx < 53248) {                // W1T [128][128]
        const int j = idx - 36864;
        const int nn = j >> 7, k = j & 127;
        ws[idx] = (_Float16)W1[k * HH + nn];
    } else if (idx < 69632) {                // W2T [128][128]
        const int j = idx - 53248;
        const int nn = j >> 7, k = j & 127;
        ws[idx] = (_Float16)W2[k * HH + nn];
    }
}

// ---------------- main fused kernel ----------------
__global__ __launch_bounds__(NT, 3) void graphcnn_mfma(
    const float* __restrict__ adj,
    const _Float16* __restrict__ wts,
    const float* __restrict__ b0, const float* __restrict__ b1,
    float* __restrict__ out)
{
    // LDS: adjH [96][104] | B1 [96][136] (tR -> uR -> YR)
    __shared__ __align__(16) unsigned char smem[46080];
    _Float16* adjH = (_Float16*)smem;
    _Float16* B1   = (_Float16*)(smem + 19968);

    const int t    = threadIdx.x;
    const int wv   = t >> 6;
    const int lane = t & 63;
    const int p    = lane & 31;
    const int h    = lane >> 5;
    const int n    = wv * 32 + p;      // hidden column owned by this thread

    const _Float16* W0T = wts;                  // [128][96]
    const _Float16* WdT = wts + 12288;          // [128][96], col90 = c1
    const _Float16* WeT = wts + 24576;          // [128][96], col90 = bsum
    const _Float16* W1T = wts + 36864;          // [128][128]
    const _Float16* W2T = wts + 53248;          // [128][128]

    // ---- stage adj fp32->fp16 with fused zero-pad (rows/cols 90..95 -> 0) ----
    {
        const float* Ag = adj + (size_t)blockIdx.x * (NN * NN);
        unsigned* aH = (unsigned*)adjH;
        #pragma unroll
        for (int it = 0; it < 18; it++) {
            const int i = t + it * NT;          // 0..4607 = 96 rows * 48 u32
            const int r = i / 48, cc = i - r * 48;
            unsigned val = 0u;
            if (r < NN && cc < 45) {
                const float2 v = *(const float2*)(Ag + r * NN + cc * 2);
                const half2v hv = { (_Float16)v.x, (_Float16)v.y };
                val = __builtin_bit_cast(unsigned, hv);
            }
            aH[r * ASTU + cc] = val;
        }
    }

    // C-registers -> row-major LDS
    auto writeR = [&](_Float16* buf, const floatx16& A0, const floatx16& A1,
                      const floatx16& A2) {
        #pragma unroll
        for (int mt = 0; mt < 3; mt++) {
            const floatx16& A = (mt == 0) ? A0 : (mt == 1) ? A1 : A2;
            #pragma unroll
            for (int r = 0; r < 16; r++) {
                const int node = mt * 32 + (r & 3) + 8 * (r >> 2) + 4 * h;
                buf[node * SR + n] = (_Float16)A[r];
            }
        }
    };

    // C-registers -> B-fragments (for next adj@X matmul), pure in-register:
    // consumer lane (p,h) needs B[k=16kt+8h+j][n]; exchange across lane^32.
    uint4v frg[6];
    auto buildFrags = [&](const floatx16& A0, const floatx16& A1, const floatx16& A2) {
        #pragma unroll
        for (int mt = 0; mt < 3; mt++) {
            const floatx16& A = (mt == 0) ? A0 : (mt == 1) ? A1 : A2;
            #pragma unroll
            for (int s01 = 0; s01 < 2; s01++) {
                const int s = 8 * s01;
                const half2v x0 = { (_Float16)A[s + 0], (_Float16)A[s + 1] };
                const half2v x1 = { (_Float16)A[s + 2], (_Float16)A[s + 3] };
                const half2v y0 = { (_Float16)A[s + 4], (_Float16)A[s + 5] };
                const half2v y1 = { (_Float16)A[s + 6], (_Float16)A[s + 7] };
                const unsigned X0 = __builtin_bit_cast(unsigned, x0);
                const unsigned X1 = __builtin_bit_cast(unsigned, x1);
                const unsigned Y0 = __builtin_bit_cast(unsigned, y0);
                const unsigned Y1 = __builtin_bit_cast(unsigned, y1);
                const unsigned R0 = __shfl_xor(h ? X0 : Y0, 32, 64);
                const unsigned R1 = __shfl_xor(h ? X1 : Y1, 32, 64);
                uint4v f;
                f[0] = h ? R0 : X0;
                f[1] = h ? R1 : X1;
                f[2] = h ? Y0 : R0;
                f[3] = h ? Y1 : R1;
                frg[mt * 2 + s01] = f;
            }
        }
    };

    __syncthreads();

    floatx16 acc0, acc1, acc2;

    // ===== S1: h0 = adj @ W0 + b0 -> B-frags only (no LDS write) =====
    {
        half8 bw[6];
        #pragma unroll
        for (int kt = 0; kt < 6; kt++) bw[kt] = ((const half8*)W0T)[n * 12 + kt * 2 + h];
        const float bias = b0[n];
        #pragma unroll
        for (int r = 0; r < 16; r++) { acc0[r] = bias; acc1[r] = bias; acc2[r] = bias; }
        #pragma unroll
        for (int kt = 0; kt < 6; kt++) {
            const half8 a0 = ((const half8*)adjH)[(0 * 32 + p) * AST8 + kt * 2 + h];
            const half8 a1 = ((const half8*)adjH)[(1 * 32 + p) * AST8 + kt * 2 + h];
            const half8 a2 = ((const half8*)adjH)[(2 * 32 + p) * AST8 + kt * 2 + h];
            acc0 = MFMA(a0, bw[kt], acc0);
            acc1 = MFMA(a1, bw[kt], acc1);
            acc2 = MFMA(a2, bw[kt], acc2);
        }
        buildFrags(acc0, acc1, acc2);
    }

    // ===== S3: t = adj @ h0 (B from regs) -> tR (B1) =====
    {
        #pragma unroll
        for (int r = 0; r < 16; r++) { acc0[r] = 0.f; acc1[r] = 0.f; acc2[r] = 0.f; }
        #pragma unroll
        for (int kt = 0; kt < 6; kt++) {
            const half8 bfk = __builtin_bit_cast(half8, frg[kt]);
            const half8 a0 = ((const half8*)adjH)[(0 * 32 + p) * AST8 + kt * 2 + h];
            const half8 a1 = ((const half8*)adjH)[(1 * 32 + p) * AST8 + kt * 2 + h];
            const half8 a2 = ((const half8*)adjH)[(2 * 32 + p) * AST8 + kt * 2 + h];
            acc0 = MFMA(a0, bfk, acc0);
            acc1 = MFMA(a1, bfk, acc1);
            acc2 = MFMA(a2, bfk, acc2);
        }
        writeR(B1, acc0, acc1, acc2);
    }

    // ===== S2': r1 = adj @ Wd + c1 -> packed fp16 regs (no h0R needed) =====
    half8 r1p[6];
    {
        half8 bw[6];
        #pragma unroll
        for (int kt = 0; kt < 6; kt++) bw[kt] = ((const half8*)WdT)[n * 12 + kt * 2 + h];
        const float bias = (float)WdT[n * 96 + 90];      // c1[n]
        floatx16 ra, rb, rc;
        #pragma unroll
        for (int r = 0; r < 16; r++) { ra[r] = bias; rb[r] = bias; rc[r] = bias; }
        #pragma unroll
        for (int kt = 0; kt < 6; kt++) {
            const half8 a0 = ((const half8*)adjH)[(0 * 32 + p) * AST8 + kt * 2 + h];
            const half8 a1 = ((const half8*)adjH)[(1 * 32 + p) * AST8 + kt * 2 + h];
            const half8 a2 = ((const half8*)adjH)[(2 * 32 + p) * AST8 + kt * 2 + h];
            ra = MFMA(a0, bw[kt], ra);
            rb = MFMA(a1, bw[kt], rb);
            rc = MFMA(a2, bw[kt], rc);
        }
        #pragma unroll
        for (int mt = 0; mt < 3; mt++) {
            const floatx16& A = (mt == 0) ? ra : (mt == 1) ? rb : rc;
            #pragma unroll
            for (int s01 = 0; s01 < 2; s01++) {
                half8 v;
                #pragma unroll
                for (int j = 0; j < 8; j++) v[j] = (_Float16)A[8 * s01 + j];
                r1p[mt * 2 + s01] = v;
            }
        }
    }
    __syncthreads();    // tR visible for S4

    // ===== S4: x = relu(tR @ W1 + b1) + r1 -> B-frags only =====
    {
        half8 bw[8];
        #pragma unroll
        for (int kt = 0; kt < 8; kt++) bw[kt] = ((const half8*)W1T)[n * 16 + kt * 2 + h];
        const float bias = b1[n];
        #pragma unroll
        for (int r = 0; r < 16; r++) { acc0[r] = bias; acc1[r] = bias; acc2[r] = bias; }
        #pragma unroll
        for (int kt = 0; kt < 8; kt++) {
            const half8 a0 = ((const half8*)B1)[(0 * 32 + p) * SR8 + kt * 2 + h];
            const half8 a1 = ((const half8*)B1)[(1 * 32 + p) * SR8 + kt * 2 + h];
            const half8 a2 = ((const half8*)B1)[(2 * 32 + p) * SR8 + kt * 2 + h];
            acc0 = MFMA(a0, bw[kt], acc0);
            acc1 = MFMA(a1, bw[kt], acc1);
            acc2 = MFMA(a2, bw[kt], acc2);
        }
        #pragma unroll
        for (int r = 0; r < 16; r++) {
            acc0[r] = fmaxf(acc0[r], 0.f) + (float)r1p[0 * 2 + (r >> 3)][r & 7];
            acc1[r] = fmaxf(acc1[r], 0.f) + (float)r1p[1 * 2 + (r >> 3)][r & 7];
            acc2[r] = fmaxf(acc2[r], 0.f) + (float)r1p[2 * 2 + (r >> 3)][r & 7];
        }
        buildFrags(acc0, acc1, acc2);
    }
    __syncthreads();    // all tR reads done before uR overwrites B1

    // ===== S5: u = adj @ x (B from regs) -> uR (B1) =====
    {
        #pragma unroll
        for (int r = 0; r < 16; r++) { acc0[r] = 0.f; acc1[r] = 0.f; acc2[r] = 0.f; }
        #pragma unroll
        for (int kt = 0; kt < 6; kt++) {
            const half8 bfk = __builtin_bit_cast(half8, frg[kt]);
            const half8 a0 = ((const half8*)adjH)[(0 * 32 + p) * AST8 + kt * 2 + h];
            const half8 a1 = ((const half8*)adjH)[(1 * 32 + p) * AST8 + kt * 2 + h];
            const half8 a2 = ((const half8*)adjH)[(2 * 32 + p) * AST8 + kt * 2 + h];
            acc0 = MFMA(a0, bfk, acc0);
            acc1 = MFMA(a1, bfk, acc1);
            acc2 = MFMA(a2, bfk, acc2);
        }
        writeR(B1, acc0, acc1, acc2);
    }
    __syncthreads();    // uR visible

    // ===== S6: Y = relu(uR@W2 + adj@We + bsum)  (h0@Wc folded to adj@We) =====
    {
        half8 bw[8];
        #pragma unroll
        for (int kt = 0; kt < 8; kt++) bw[kt] = ((const half8*)W2T)[n * 16 + kt * 2 + h];
        const float bias = (float)WeT[n * 96 + 90];      // bsum[n]
        #pragma unroll
        for (int r = 0; r < 16; r++) { acc0[r] = bias; acc1[r] = bias; acc2[r] = bias; }
        #pragma unroll
        for (int kt = 0; kt < 8; kt++) {
            const half8 a0 = ((const half8*)B1)[(0 * 32 + p) * SR8 + kt * 2 + h];
            const half8 a1 = ((const half8*)B1)[(1 * 32 + p) * SR8 + kt * 2 + h];
            const half8 a2 = ((const half8*)B1)[(2 * 32 + p) * SR8 + kt * 2 + h];
            acc0 = MFMA(a0, bw[kt], acc0);
            acc1 = MFMA(a1, bw[kt], acc1);
            acc2 = MFMA(a2, bw[kt], acc2);
        }
        half8 bg[6];
        #pragma unroll
        for (int kt = 0; kt < 6; kt++) bg[kt] = ((const half8*)WeT)[n * 12 + kt * 2 + h];
        #pragma unroll
        for (int kt = 0; kt < 6; kt++) {
            const half8 a0 = ((const half8*)adjH)[(0 * 32 + p) * AST8 + kt * 2 + h];
            const half8 a1 = ((const half8*)adjH)[(1 * 32 + p) * AST8 + kt * 2 + h];
            const half8 a2 = ((const half8*)adjH)[(2 * 32 + p) * AST8 + kt * 2 + h];
            acc0 = MFMA(a0, bg[kt], acc0);
            acc1 = MFMA(a1, bg[kt], acc1);
            acc2 = MFMA(a2, bg[kt], acc2);
        }
    }
    __syncthreads();    // all uR reads done before YR overwrites B1
    {
        _Float16* YR = B1;
        #pragma unroll
        for (int mt = 0; mt < 3; mt++) {
            const floatx16& A = (mt == 0) ? acc0 : (mt == 1) ? acc1 : acc2;
            #pragma unroll
            for (int r = 0; r < 16; r++) {
                const int node = mt * 32 + (r & 3) + 8 * (r >> 2) + 4 * h;
                YR[node * SR + n] = (_Float16)fmaxf(A[r], 0.f);
            }
        }
    }
    __syncthreads();

    // ===== S7: Z = Y @ Y^T -> out (both operands from YR row-major) =====
    {
        const _Float16* YR = B1;
        float* outb = out + (size_t)blockIdx.x * (NN * NN);
        auto ztile = [&](int mt, int nt) {
            floatx16 acc;
            #pragma unroll
            for (int r = 0; r < 16; r++) acc[r] = 0.f;
            #pragma unroll
            for (int kt = 0; kt < 8; kt++) {
                const half8 av = ((const half8*)YR)[(mt * 32 + p) * SR8 + kt * 2 + h];
                const half8 bv = ((const half8*)YR)[(nt * 32 + p) * SR8 + kt * 2 + h];
                acc = MFMA(av, bv, acc);
            }
            const int col = nt * 32 + p;
            if (col < NN) {
                #pragma unroll
                for (int r = 0; r < 16; r++) {
                    const int row = mt * 32 + (r & 3) + 8 * (r >> 2) + 4 * h;
                    if (row < NN) outb[row * NN + col] = acc[r];
                }
            }
        };
        if      (wv == 0) { ztile(0, 0); ztile(0, 1); ztile(0, 2); }
        else if (wv == 1) { ztile(1, 0); ztile(1, 1); }
        else if (wv == 2) { ztile(1, 2); ztile(2, 0); }
        else              { ztile(2, 1); ztile(2, 2); }
    }
}

extern "C" void kernel_launch(void* const* d_in, const int* in_sizes, int n_in,
                              void* d_out, int out_size, void* d_ws, size_t ws_size,
                              hipStream_t stream) {
    const float* adj = (const float*)d_in[0];
    const float* W0  = (const float*)d_in[1];
    const float* b0  = (const float*)d_in[2];
    const float* W1  = (const float*)d_in[3];
    const float* b1  = (const float*)d_in[4];
    const float* W2  = (const float*)d_in[5];
    const float* b2  = (const float*)d_in[6];
    const float* Wr1 = (const float*)d_in[7];
    const float* br1 = (const float*)d_in[8];
    const float* Wr2 = (const float*)d_in[9];
    const float* br2 = (const float*)d_in[10];
    float* out = (float*)d_out;
    _Float16* wts = (_Float16*)d_ws;

    float* WdF = (float*)((char*)d_ws + 139264);   // [90][128] fp32
    float* c1F = (float*)((char*)d_ws + 185344);   // [128] fp32

    prep_stage1<<<12, 1024, 0, stream>>>(W0, Wr1, b0, br1, WdF, c1F);
    prep_stage2<<<68, 1024, 0, stream>>>(W0, W1, W2, Wr2, b2, br2, WdF, c1F, wts);

    const int B = in_sizes[0] / (NN * NN);
    graphcnn_mfma<<<B, NT, 0, stream>>>(adj, wts, b0, b1, out);
}